// Round 1
// baseline (4312.682 us; speedup 1.0000x reference)
//
#include <hip/hip_runtime.h>
#include <math.h>

#define Bq 16
#define Tq 32
#define Wq 128
#define Rq 4
#define Nq 512
#define Mq 128
#define DINq 768
#define XIDq 919
#define XIPq 920
#define BTWq (Bq*Tq*Wq)

struct P {
  const float *X, *hs0, *mem0;
  const int *rst;
  const float *Wb,*bb,*Wff1,*bff1,*Wff2,*bff2,*Wta,*bta,*Wtb,*btb,*Wv,*bv,*Wr,*br,*Wxi,*bxi;
  float *out;
  float *memv,*link,*fwpart,*bw,*rw,*hs,*reads,*ww,*usage,*prec0,*prec1,*norms,*xi,*z;
  float *WbT,*Wff1T,*Wff2T,*WtaT,*WtbT,*WvT,*WrT,*WxiT;
};

__device__ __forceinline__ float dot4(float4 a, float4 b){
  return a.x*b.x + a.y*b.y + a.z*b.z + a.w*b.w;
}
__device__ __forceinline__ float sigf(float x){ return 1.f/(1.f+expf(-x)); }
__device__ __forceinline__ float oneplusf(float x){ return 1.f + log1pf(expf(x) + 1e-6f); }

__device__ __forceinline__ float bsum512(float v, float* buf){
  int tid = threadIdx.x;
  buf[tid]=v; __syncthreads();
  #pragma unroll
  for (int s=256;s>0;s>>=1){ if (tid<s) buf[tid]+=buf[tid+s]; __syncthreads(); }
  float r = buf[0]; __syncthreads(); return r;
}
__device__ __forceinline__ float bmax512(float v, float* buf){
  int tid = threadIdx.x;
  buf[tid]=v; __syncthreads();
  #pragma unroll
  for (int s=256;s>0;s>>=1){ if (tid<s) buf[tid]=fmaxf(buf[tid],buf[tid+s]); __syncthreads(); }
  float r = buf[0]; __syncthreads(); return r;
}

// ---------------- init: copy state, zero buffers, transpose weights ----------------
__global__ __launch_bounds__(256) void k_init(P p){
  int bid = blockIdx.x, tid = threadIdx.x;
  if (bid < 32){
    // memv copy + row norms (one thread per row), 8192 rows
    int gid = bid*256 + tid;
    const float4* src = (const float4*)(p.mem0 + (size_t)gid*Mq);
    float4* dst = (float4*)(p.memv + (size_t)gid*Mq);
    float s = 0.f;
    #pragma unroll 8
    for (int c=0;c<32;c++){ float4 v = src[c]; dst[c]=v; s += dot4(v,v); }
    p.norms[gid] = sqrtf(s);
  } else if (bid < 224){
    float4* L = (float4*)p.link;
    int idx = (bid-32)*256 + tid; int stride = 192*256;
    float4 z4 = make_float4(0.f,0.f,0.f,0.f);
    for (int i=idx; i<(Bq*Nq*Nq)/4; i+=stride) L[i] = z4;
  } else if (bid == 224){
    for (int i=tid;i<Bq*Nq;i+=256){ p.usage[i]=0.f; p.prec0[i]=0.f; p.prec1[i]=0.f; p.ww[i]=0.f; }
    for (int i=tid;i<Bq*Rq*Nq;i+=256) p.rw[i]=0.f;
    for (int i=tid;i<Bq*Rq*Wq;i+=256) p.reads[i]=0.f;
    for (int i=tid;i<Bq*Wq;i+=256) p.hs[i]=p.hs0[i];
  } else if (bid < 233){            // WbT: (768,128) -> (128,768)
    int idx=(bid-225)*256+tid, stride=8*256;
    for (int k=idx;k<DINq*Wq;k+=stride){ int j=k/DINq, i=k%DINq; p.WbT[k]=p.Wb[i*Wq+j]; }
  } else if (bid < 235){
    int idx=(bid-233)*256+tid, stride=2*256;
    for (int k=idx;k<Wq*Wq;k+=stride){ int j=k/Wq, i=k%Wq; p.Wff1T[k]=p.Wff1[i*Wq+j]; }
  } else if (bid < 237){
    int idx=(bid-235)*256+tid, stride=2*256;
    for (int k=idx;k<Wq*Wq;k+=stride){ int j=k/Wq, i=k%Wq; p.Wff2T[k]=p.Wff2[i*Wq+j]; }
  } else if (bid < 239){
    int idx=(bid-237)*256+tid, stride=2*256;
    for (int k=idx;k<Wq*Wq;k+=stride){ int j=k/Wq, i=k%Wq; p.WtaT[k]=p.Wta[i*Wq+j]; }
  } else if (bid < 241){
    int idx=(bid-239)*256+tid, stride=2*256;
    for (int k=idx;k<Wq*Wq;k+=stride){ int j=k/Wq, i=k%Wq; p.WtbT[k]=p.Wtb[i*Wq+j]; }
  } else if (bid < 243){
    int idx=(bid-241)*256+tid, stride=2*256;
    for (int k=idx;k<Wq*Wq;k+=stride){ int j=k/Wq, i=k%Wq; p.WvT[k]=p.Wv[i*Wq+j]; }
  } else if (bid < 247){            // WrT: (512,128) -> (128,512)
    int idx=(bid-243)*256+tid, stride=4*256;
    for (int k=idx;k<Rq*Wq*Wq;k+=stride){ int j=k/(Rq*Wq), i=k%(Rq*Wq); p.WrT[k]=p.Wr[i*Wq+j]; }
  } else if (bid < 255){            // WxiT: (128,919) -> (919,128)
    int idx=(bid-247)*256+tid, stride=8*256;
    for (int k=idx;k<XIDq*Wq;k+=stride){ int f=k/Wq, i=k%Wq; p.WxiT[k]=p.Wxi[i*XIDq+f]; }
  }
}

// ---------------- z = silu([x, prev_reads, hs*(1-r)] @ Wb + bb) ----------------
__global__ __launch_bounds__(256) void k_z(P p, int t){
  int gid = blockIdx.x*256 + threadIdx.x;   // 2048 = 16b x 128j
  int b = gid & 15, j = gid >> 4;
  float keep = 1.f - (float)p.rst[b*Tq + t];
  const float4* wr = (const float4*)(p.WbT + (size_t)j*DINq);
  const float4* xr = (const float4*)(p.X + ((size_t)(b*Tq + t))*Wq);
  const float4* rr = (const float4*)(p.reads + (size_t)b*Rq*Wq);
  const float4* hr = (const float4*)(p.hs + (size_t)b*Wq);
  float acc = p.bb[j];
  #pragma unroll 8
  for (int c=0;c<32;c++) acc += dot4(wr[c], xr[c]);
  #pragma unroll 8
  for (int c=0;c<128;c++) acc += dot4(wr[32+c], rr[c]);
  float ah = 0.f;
  #pragma unroll 8
  for (int c=0;c<32;c++) ah += dot4(wr[160+c], hr[c]);
  acc += keep*ah;
  p.z[b*Wq + j] = acc * sigf(acc);
}

// ---------------- hs = ff1*(1-ti)+ti*ff2 ----------------
__global__ __launch_bounds__(256) void k_hs(P p, int t){
  int gid = blockIdx.x*256 + threadIdx.x;
  int b = gid & 15, j = gid >> 4;
  const float4* zr = (const float4*)(p.z + b*Wq);
  const float4* w1 = (const float4*)(p.Wff1T + j*Wq);
  const float4* w2 = (const float4*)(p.Wff2T + j*Wq);
  const float4* wa = (const float4*)(p.WtaT + j*Wq);
  const float4* wb = (const float4*)(p.WtbT + j*Wq);
  float a1=p.bff1[j], a2=p.bff2[j], aa=p.bta[j], ab=p.btb[j];
  #pragma unroll 4
  for (int c=0;c<32;c++){
    float4 zv = zr[c];
    a1 += dot4(w1[c], zv); a2 += dot4(w2[c], zv);
    aa += dot4(wa[c], zv); ab += dot4(wb[c], zv);
  }
  float ti = sigf(aa*(float)t + ab);
  float h = a1*(1.f-ti) + ti*a2;
  p.hs[b*Wq+j] = h;
  p.out[BTWq + ((size_t)b*Tq + t)*Wq + j] = h;
}

// ---------------- xi = hs @ Wxi + bxi (raw, activations applied by consumers) ----------------
__global__ __launch_bounds__(256) void k_xi(P p, int t){
  int gid = blockIdx.x*256 + threadIdx.x;
  int f = gid >> 4, b = gid & 15;
  if (f >= XIDq) return;
  const float4* hr = (const float4*)(p.hs + b*Wq);
  const float4* wr = (const float4*)(p.WxiT + (size_t)f*Wq);
  float acc = p.bxi[f];
  #pragma unroll 8
  for (int c=0;c<32;c++) acc += dot4(wr[c], hr[c]);
  p.xi[b*XIPq + f] = acc;
}

// ---------------- per-batch: wca, retention, usage, sort, alloc, ww, prec ----------------
__global__ __launch_bounds__(512) void k_addr(P p, int t){
  int b = blockIdx.x, tid = threadIdx.x;
  __shared__ float key[Wq];
  __shared__ float rbuf[512];
  __shared__ float uarr[512];
  __shared__ float cp[512];
  __shared__ float wcas[512];
  __shared__ unsigned long long sk[512];
  const float* xib = p.xi + b*XIPq;
  float keep = 1.f - (float)p.rst[b*Tq + t];
  if (tid < Wq) key[tid] = xib[512 + tid];
  __syncthreads();
  float pk = (tid < Wq) ? key[tid]*key[tid] : 0.f;
  float kn = sqrtf(bsum512(pk, rbuf));
  // write-content sim for row n = tid
  const float4* k4 = (const float4*)key;
  const float4* mrow = (const float4*)(p.memv + ((size_t)b*Nq + tid)*Mq);
  float d = 0.f;
  #pragma unroll 8
  for (int c=0;c<32;c++) d += dot4(k4[c], mrow[c]);
  float mn = p.norms[b*Nq + tid];
  float sim = (keep*d) / (kn*(keep*mn) + 1e-6f);
  float wstr = oneplusf(xib[916]);
  float v = wstr*sim;
  float mx = bmax512(v, rbuf);
  float e = expf(v - mx);
  float se = bsum512(e, rbuf);
  wcas[tid] = e/se;
  // retention and usage update
  float ret = 1.f;
  #pragma unroll
  for (int rr=0;rr<Rq;rr++){
    float fg = sigf(xib[896+rr]);
    ret *= 1.f - fg * p.rw[((size_t)b*Rq+rr)*Nq + tid];
  }
  float uo = p.usage[b*Nq+tid], pw = p.ww[b*Nq+tid];
  float u = (uo + pw - uo*pw)*ret;
  p.usage[b*Nq+tid] = u;
  uarr[tid] = u;
  // stable ascending argsort via (bits(u) << 32 | idx); u >= 0 so bits are monotone
  sk[tid] = ((unsigned long long)__float_as_uint(u) << 32) | (unsigned)tid;
  __syncthreads();
  for (int k=2;k<=512;k<<=1){
    for (int j=k>>1;j>0;j>>=1){
      int ixj = tid ^ j;
      if (ixj > tid){
        unsigned long long a = sk[tid], c = sk[ixj];
        bool up = (tid & k)==0;
        if (up ? (a>c) : (a<c)){ sk[tid]=c; sk[ixj]=a; }
      }
      __syncthreads();
    }
  }
  // inclusive cumprod of sorted usage
  cp[tid] = __uint_as_float((unsigned)(sk[tid]>>32));
  __syncthreads();
  for (int off=1; off<512; off<<=1){
    float prev = (tid>=off)? cp[tid-off] : 1.f;
    __syncthreads();
    cp[tid] *= prev;
    __syncthreads();
  }
  int si = (int)(sk[tid] & 0xffffffffULL);   // si[tid]: orig index of rank-tid element
  float alloc = (1.f - uarr[tid]) * cp[si];  // reference's cp[si[k]] indexing, replicated
  float ag = sigf(xib[917]);
  float wg = sigf(xib[918]);
  float wwv = wg*(ag*alloc + (1.f-ag)*wcas[tid]);
  p.ww[b*Nq+tid] = wwv;
  float wsum = bsum512(wwv, rbuf);
  const float* po = (t&1)? p.prec1 : p.prec0;
  float* pn = (t&1)? p.prec0 : p.prec1;
  pn[b*Nq+tid] = (1.f - wsum)*po[b*Nq+tid] + wwv;
}

// ---------------- link update + fw/bw partials (blocks 0..255) ; mem update + norms (256..287) ----------------
__global__ __launch_bounds__(256) void k_link(P p, int t){
  int bid = blockIdx.x, tid = threadIdx.x;
  const float* po = (t&1)? p.prec1 : p.prec0;
  if (bid < 256){
    int b = bid>>4, tile = bid&15, n0 = tile*32;
    int wave = tid>>6, lane = tid&63;
    int c0 = lane*8;
    const float* wwb = p.ww + b*Nq;
    __shared__ float fwtmp[4][Rq][Nq];   // 32 KB
    float ww8[8], pc8[8], pr8[Rq][8];
    *(float4*)&ww8[0] = *(const float4*)(wwb + c0);
    *(float4*)&ww8[4] = *(const float4*)(wwb + c0 + 4);
    *(float4*)&pc8[0] = *(const float4*)(po + b*Nq + c0);
    *(float4*)&pc8[4] = *(const float4*)(po + b*Nq + c0 + 4);
    #pragma unroll
    for (int r=0;r<Rq;r++){
      *(float4*)&pr8[r][0] = *(const float4*)(p.rw + ((size_t)b*Rq+r)*Nq + c0);
      *(float4*)&pr8[r][4] = *(const float4*)(p.rw + ((size_t)b*Rq+r)*Nq + c0 + 4);
    }
    float fa[Rq][8];
    #pragma unroll
    for (int r=0;r<Rq;r++)
      #pragma unroll
      for (int q=0;q<8;q++) fa[r][q]=0.f;
    for (int rr=0; rr<8; rr++){
      int n = n0 + wave*8 + rr;
      float wwn = wwb[n];
      float prn[Rq];
      #pragma unroll
      for (int r=0;r<Rq;r++) prn[r] = p.rw[((size_t)b*Rq+r)*Nq + n];
      size_t row = ((size_t)b*Nq + n)*Nq;
      float4 La = *(const float4*)(p.link + row + c0);
      float4 Lb = *(const float4*)(p.link + row + c0 + 4);
      float vv[8] = {La.x,La.y,La.z,La.w,Lb.x,Lb.y,Lb.z,Lb.w};
      float bwp[Rq] = {0.f,0.f,0.f,0.f};
      #pragma unroll
      for (int q=0;q<8;q++){
        float nv = (1.f - wwn - ww8[q])*vv[q] + wwn*pc8[q];
        if (c0 + q == n) nv = 0.f;
        vv[q] = nv;
        #pragma unroll
        for (int r=0;r<Rq;r++){ fa[r][q] += prn[r]*nv; bwp[r] += pr8[r][q]*nv; }
      }
      *(float4*)(p.link + row + c0)     = make_float4(vv[0],vv[1],vv[2],vv[3]);
      *(float4*)(p.link + row + c0 + 4) = make_float4(vv[4],vv[5],vv[6],vv[7]);
      #pragma unroll
      for (int m=1;m<64;m<<=1)
        #pragma unroll
        for (int r=0;r<Rq;r++) bwp[r] += __shfl_xor(bwp[r], m, 64);
      if (lane==0){
        #pragma unroll
        for (int r=0;r<Rq;r++) p.bw[((size_t)b*Rq+r)*Nq + n] = bwp[r];
      }
    }
    #pragma unroll
    for (int r=0;r<Rq;r++)
      #pragma unroll
      for (int q=0;q<8;q++) fwtmp[wave][r][c0+q] = fa[r][q];
    __syncthreads();
    for (int i=tid; i<Rq*Nq; i+=256){
      int r = i>>9, k = i&511;
      float s = fwtmp[0][r][k]+fwtmp[1][r][k]+fwtmp[2][r][k]+fwtmp[3][r][k];
      p.fwpart[(((size_t)b*16 + tile)*Rq + r)*Nq + k] = s;
    }
  } else {
    int idx = bid-256; int b = idx>>1, mt = idx&1;
    __shared__ float er[Mq], wv[Mq];
    const float* xib = p.xi + b*XIPq;
    if (tid < Mq){ er[tid] = sigf(xib[768+tid]); wv[tid] = xib[640+tid]; }
    __syncthreads();
    int n = mt*256 + tid;
    float keep = 1.f - (float)p.rst[b*Tq + t];
    float wwn = p.ww[b*Nq+n];
    float4* mrow = (float4*)(p.memv + ((size_t)b*Nq+n)*Mq);
    const float4* er4 = (const float4*)er;
    const float4* wv4 = (const float4*)wv;
    float s = 0.f;
    #pragma unroll 4
    for (int c=0;c<32;c++){
      float4 mv = mrow[c], e4 = er4[c], w4 = wv4[c];
      mv.x = mv.x*keep*(1.f - wwn*e4.x) + wwn*w4.x;
      mv.y = mv.y*keep*(1.f - wwn*e4.y) + wwn*w4.y;
      mv.z = mv.z*keep*(1.f - wwn*e4.z) + wwn*w4.z;
      mv.w = mv.w*keep*(1.f - wwn*e4.w) + wwn*w4.w;
      s += dot4(mv,mv);
      mrow[c] = mv;
    }
    p.norms[b*Nq+n] = sqrtf(s);
  }
}

// ---------------- rca softmax + rw combine, per (b,r) ----------------
__global__ __launch_bounds__(512) void k_rw(P p, int t){
  int b = blockIdx.x>>2, r = blockIdx.x&3, tid = threadIdx.x;
  __shared__ float key[Wq];
  __shared__ float rbuf[512];
  const float* xib = p.xi + b*XIPq;
  if (tid < Wq) key[tid] = xib[r*Wq + tid];
  __syncthreads();
  float pk = (tid < Wq) ? key[tid]*key[tid] : 0.f;
  float kn = sqrtf(bsum512(pk, rbuf));
  const float4* k4 = (const float4*)key;
  const float4* mrow = (const float4*)(p.memv + ((size_t)b*Nq + tid)*Mq);
  float d = 0.f;
  #pragma unroll 8
  for (int c=0;c<32;c++) d += dot4(k4[c], mrow[c]);
  float sim = d / (kn * p.norms[b*Nq+tid] + 1e-6f);
  float rstr = oneplusf(xib[900+r]);
  float v = rstr*sim;
  float mx = bmax512(v, rbuf);
  float e = expf(v - mx);
  float se = bsum512(e, rbuf);
  float rca = e/se;
  float fw = 0.f;
  #pragma unroll
  for (int tl=0; tl<16; tl++) fw += p.fwpart[(((size_t)b*16+tl)*Rq + r)*Nq + tid];
  float bw = p.bw[((size_t)b*Rq + r)*Nq + tid];
  float m0 = xib[904+r*3], m1 = xib[905+r*3], m2 = xib[906+r*3];
  float mm = fmaxf(m0, fmaxf(m1,m2));
  float e0=expf(m0-mm), e1=expf(m1-mm), e2=expf(m2-mm);
  float es = e0+e1+e2;
  float rwv = (e0*bw + e1*rca + e2*fw)/es;
  p.rw[((size_t)b*Rq+r)*Nq + tid] = rwv;
}

// ---------------- reads = rw @ memv ; y = hs@Wv + bv + reads@Wr + br ----------------
__global__ __launch_bounds__(512) void k_reads(P p, int t){
  int b = blockIdx.x, tid = threadIdx.x;
  int r = tid>>7, m = tid&127;
  __shared__ float rds[Rq*Wq];
  const float* rwb = p.rw + ((size_t)b*Rq + r)*Nq;
  const float* mb = p.memv + (size_t)b*Nq*Mq + m;
  float acc = 0.f;
  #pragma unroll 8
  for (int n=0;n<Nq;n++) acc += rwb[n]*mb[(size_t)n*Mq];
  rds[tid] = acc;
  p.reads[b*Rq*Wq + tid] = acc;
  __syncthreads();
  if (tid < Wq){
    int j = tid;
    float y = p.bv[j] + p.br[j];
    const float4* wv4 = (const float4*)(p.WvT + j*Wq);
    const float4* h4  = (const float4*)(p.hs + b*Wq);
    #pragma unroll 8
    for (int c=0;c<32;c++) y += dot4(wv4[c], h4[c]);
    const float4* wr4 = (const float4*)(p.WrT + (size_t)j*(Rq*Wq));
    const float4* rd4 = (const float4*)rds;
    #pragma unroll 8
    for (int c=0;c<128;c++) y += dot4(wr4[c], rd4[c]);
    p.out[((size_t)b*Tq + t)*Wq + j] = y;
  }
}

extern "C" void kernel_launch(void* const* d_in, const int* in_sizes, int n_in,
                              void* d_out, int out_size, void* d_ws, size_t ws_size,
                              hipStream_t stream){
  (void)in_sizes; (void)n_in; (void)out_size; (void)ws_size;
  P p;
  p.X    = (const float*)d_in[0];
  p.hs0  = (const float*)d_in[1];
  p.mem0 = (const float*)d_in[2];
  p.rst  = (const int*)d_in[3];
  p.Wb   = (const float*)d_in[4];  p.bb   = (const float*)d_in[5];
  p.Wff1 = (const float*)d_in[6];  p.bff1 = (const float*)d_in[7];
  p.Wff2 = (const float*)d_in[8];  p.bff2 = (const float*)d_in[9];
  p.Wta  = (const float*)d_in[10]; p.bta  = (const float*)d_in[11];
  p.Wtb  = (const float*)d_in[12]; p.btb  = (const float*)d_in[13];
  p.Wv   = (const float*)d_in[14]; p.bv   = (const float*)d_in[15];
  p.Wr   = (const float*)d_in[16]; p.br   = (const float*)d_in[17];
  p.Wxi  = (const float*)d_in[18]; p.bxi  = (const float*)d_in[19];
  p.out = (float*)d_out;
  float* ws = (float*)d_ws;
  size_t o = 0;
  p.memv   = ws + o; o += (size_t)Bq*Nq*Mq;       // 1,048,576
  p.link   = ws + o; o += (size_t)Bq*Nq*Nq;       // 4,194,304
  p.fwpart = ws + o; o += (size_t)Bq*16*Rq*Nq;    //   524,288
  p.bw     = ws + o; o += (size_t)Bq*Rq*Nq;
  p.rw     = ws + o; o += (size_t)Bq*Rq*Nq;
  p.hs     = ws + o; o += (size_t)Bq*Wq;
  p.reads  = ws + o; o += (size_t)Bq*Rq*Wq;
  p.ww     = ws + o; o += (size_t)Bq*Nq;
  p.usage  = ws + o; o += (size_t)Bq*Nq;
  p.prec0  = ws + o; o += (size_t)Bq*Nq;
  p.prec1  = ws + o; o += (size_t)Bq*Nq;
  p.norms  = ws + o; o += (size_t)Bq*Nq;
  p.xi     = ws + o; o += (size_t)Bq*XIPq;
  p.z      = ws + o; o += (size_t)Bq*Wq;
  p.WbT    = ws + o; o += (size_t)DINq*Wq;
  p.Wff1T  = ws + o; o += (size_t)Wq*Wq;
  p.Wff2T  = ws + o; o += (size_t)Wq*Wq;
  p.WtaT   = ws + o; o += (size_t)Wq*Wq;
  p.WtbT   = ws + o; o += (size_t)Wq*Wq;
  p.WvT    = ws + o; o += (size_t)Wq*Wq;
  p.WrT    = ws + o; o += (size_t)Rq*Wq*Wq;
  p.WxiT   = ws + o; o += (size_t)XIDq*Wq;

  hipLaunchKernelGGL(k_init, dim3(320), dim3(256), 0, stream, p);
  for (int t=0; t<Tq; t++){
    hipLaunchKernelGGL(k_z,     dim3(8),   dim3(256), 0, stream, p, t);
    hipLaunchKernelGGL(k_hs,    dim3(8),   dim3(256), 0, stream, p, t);
    hipLaunchKernelGGL(k_xi,    dim3(58),  dim3(256), 0, stream, p, t);
    hipLaunchKernelGGL(k_addr,  dim3(16),  dim3(512), 0, stream, p, t);
    hipLaunchKernelGGL(k_link,  dim3(288), dim3(256), 0, stream, p, t);
    hipLaunchKernelGGL(k_rw,    dim3(64),  dim3(512), 0, stream, p, t);
    hipLaunchKernelGGL(k_reads, dim3(16),  dim3(512), 0, stream, p, t);
  }
}